// Round 7
// baseline (87.484 us; speedup 1.0000x reference)
//
#include <hip/hip_runtime.h>

#define BATCH   256
#define FG_CAP  64
#define BG_CAP  192
#define NB_CAP  256
#define M_ROIS  2          // ROIs register-tiled per thread
#define GRP     8          // lanes per slice-group (k mod 8)
#define ROIS_PB (32 * M_ROIS)   // 64 ROIs per 256-thread block
#define KV_SENTINEL (-1)

// ---------------------------------------------------------------------------
// Kernel 1: per-ROI IoU argmax vs all GT boxes (R6-verified: M=2 register
// tile, 1 ds_read_b128 per 2 roi-items, area_g recomputed with identical _rn
// sequence). Trailing blocks: gt one-hot argmax + keep_arr sentinel init
// (kernel-end flush makes it device-visible before the next dispatch).
// Division-free compare (R4-verified); one __fdiv_rn on the winner for the
// numpy-exact 0.5/0.1 threshold test. packed[i]=bestk|cls<<16 (0/1 fg/2 bg).
// ---------------------------------------------------------------------------
__global__ __launch_bounds__(256) void pt_classify(
    const float* __restrict__ props, const float* __restrict__ gtb,
    const float* __restrict__ gtl,
    int* __restrict__ packed, int* __restrict__ gtcls,
    int* __restrict__ keep_arr,
    int n_prop, int K, int C, int n_total, int roi_blocks)
{
    if ((int)blockIdx.x >= roi_blocks) {
        int t = ((int)blockIdx.x - roi_blocks) * 256 + (int)threadIdx.x;
        if (t < BATCH) keep_arr[t] = KV_SENTINEL;   // sentinel for kernel 2 handoff
        if (t < K) {
            const float* row = gtl + (size_t)t * C;
            float best = row[0]; int bc = 0;
            for (int c = 1; c < C; ++c) {
                float v = row[c];
                if (v > best) { best = v; bc = c; }
            }
            gtcls[t] = bc;
        }
        return;
    }

    __shared__ float4 s_gt[512];
    for (int k = threadIdx.x; k < K; k += 256)
        s_gt[k] = ((const float4*)gtb)[k];
    __syncthreads();

    const int grp   = (int)threadIdx.x >> 3;       // 0..31
    const int slice = (int)threadIdx.x & (GRP - 1);

    float4 a[M_ROIS]; float area_a[M_ROIS]; int ri[M_ROIS]; bool live[M_ROIS];
    #pragma unroll
    for (int m = 0; m < M_ROIS; ++m) {
        int i = (int)blockIdx.x * ROIS_PB + m * 32 + grp;
        ri[m] = i; live[m] = (i < n_total);
        if (live[m]) {
            a[m] = (i < n_prop) ? ((const float4*)props)[i]
                                : ((const float4*)gtb)[i - n_prop];
        } else {
            a[m] = make_float4(0.f, 0.f, 0.f, 0.f);
        }
        area_a[m] = __fmul_rn(__fadd_rn(__fsub_rn(a[m].z, a[m].x), 1.0f),
                              __fadd_rn(__fsub_rn(a[m].w, a[m].y), 1.0f));
    }

    float bi[M_ROIS], bd[M_ROIS]; int bk[M_ROIS];
    #pragma unroll
    for (int m = 0; m < M_ROIS; ++m) { bi[m] = -1.0f; bd[m] = 1.0f; bk[m] = 0x7FFFFFFF; }

    #pragma unroll 4
    for (int k = slice; k < K; k += GRP) {
        float4 g = s_gt[k];
        float area_g = __fmul_rn(__fadd_rn(__fsub_rn(g.z, g.x), 1.0f),
                                 __fadd_rn(__fsub_rn(g.w, g.y), 1.0f));
        #pragma unroll
        for (int m = 0; m < M_ROIS; ++m) {
            float iw = fmaxf(__fadd_rn(__fsub_rn(fminf(a[m].z, g.z), fmaxf(a[m].x, g.x)), 1.0f), 0.0f);
            float ih = fmaxf(__fadd_rn(__fsub_rn(fminf(a[m].w, g.w), fmaxf(a[m].y, g.y)), 1.0f), 0.0f);
            float inter = __fmul_rn(iw, ih);
            float denom = __fsub_rn(__fadd_rn(area_a[m], area_g), inter);
            if (inter * bd[m] > bi[m] * denom) { bi[m] = inter; bd[m] = denom; bk[m] = k; }
        }
    }

    #pragma unroll
    for (int mask = 1; mask < GRP; mask <<= 1) {
        #pragma unroll
        for (int m = 0; m < M_ROIS; ++m) {
            float oi = __shfl_xor(bi[m], mask, 64);
            float od = __shfl_xor(bd[m], mask, 64);
            int   ok = __shfl_xor(bk[m], mask, 64);
            float lhs = oi * bd[m], rhs = bi[m] * od;
            if (lhs > rhs || (lhs == rhs && ok < bk[m])) { bi[m] = oi; bd[m] = od; bk[m] = ok; }
        }
    }

    if (slice == 0) {
        #pragma unroll
        for (int m = 0; m < M_ROIS; ++m) {
            if (live[m]) {
                float iou = __fdiv_rn(bi[m], bd[m]);
                int cls = 0;
                if (iou >= 0.5f)      cls = 1;
                else if (iou >= 0.1f) cls = 2;
                packed[ri[m]] = bk[m] | (cls << 16);
            }
        }
    }
}

// ---------------------------------------------------------------------------
// Kernel 2: 1 + BATCH blocks, 256 threads.
// Block 0: stable index-ordered compaction (R4-verified ballot-rank logic,
//   4096 idx/round = 16 items/thread, lists in LDS, early exit at 64 fg +
//   192 bg), then publishes keep|(is_fg<<30) per slot via atomicExch
//   (coherence-point write — no fences; R3 showed per-block __threadfence
//   costs ~60 µs device-wide).
// Blocks 1..BATCH: slot s = bx-1. Thread 0 polls keep_arr[s] (atomicAdd(,0)
//   = coherent read) against the sentinel classify wrote, then all 256
//   threads produce rois / one-hot labels / bbox_targets for slot s.
//   All other inputs (packed, gtcls, props, gtb) are prior-dispatch data —
//   visible without fences. Co-residency: 257 blocks x 4 waves trivially
//   fits 256 CUs at any VGPR count -> no deadlock.
// ---------------------------------------------------------------------------
__global__ __launch_bounds__(256) void pt_select_out(
    const float* __restrict__ props, const float* __restrict__ gtb,
    const int* __restrict__ packed, const int* __restrict__ gtcls,
    int* __restrict__ keep_arr,
    float* __restrict__ out, int n_prop, int K, int C, int n_total)
{
    const int tid = (int)threadIdx.x;

    if (blockIdx.x == 0) {
        // ---------------- compaction ----------------
        __shared__ int l_fg[FG_CAP], l_bg[BG_CAP], l_nb[NB_CAP];
        __shared__ int w_f[4], w_b[4], w_n[4];
        __shared__ int s_run[3], s_stop;
        if (tid == 0) { s_run[0] = 0; s_run[1] = 0; s_run[2] = 0; s_stop = 0; }
        __syncthreads();

        const int lane = tid & 63, wave = tid >> 6;
        const unsigned long long ltm = (1ull << lane) - 1ull;

        for (int base = 0; base < n_total; base += 4096) {
            int idx0 = base + tid * 16;
            unsigned int code = 0;          // 16 items x 2 bits: 0 none,1 fg,2 bg,3 oob
            if (idx0 + 15 < n_total) {
                #pragma unroll
                for (int q = 0; q < 4; ++q) {
                    int4 p = ((const int4*)packed)[(idx0 >> 2) + q];
                    code |= (unsigned int)((p.x >> 16) & 3) << (8*q + 0);
                    code |= (unsigned int)((p.y >> 16) & 3) << (8*q + 2);
                    code |= (unsigned int)((p.z >> 16) & 3) << (8*q + 4);
                    code |= (unsigned int)((p.w >> 16) & 3) << (8*q + 6);
                }
            } else {
                #pragma unroll
                for (int j = 0; j < 16; ++j) {
                    unsigned int c = (idx0 + j < n_total) ? (unsigned int)((packed[idx0 + j] >> 16) & 3) : 3u;
                    code |= c << (2 * j);
                }
            }

            int eF = 0, eB = 0, eN = 0, tF = 0, tB = 0, tN = 0;
            #pragma unroll
            for (int j = 0; j < 16; ++j) {
                unsigned int c = (code >> (2 * j)) & 3u;
                unsigned long long bF = __ballot(c == 1u);
                unsigned long long bB = __ballot(c == 2u);
                unsigned long long bN = __ballot(c <= 1u);   // in-range, not bg
                eF += (int)__popcll(bF & ltm); tF += (int)__popcll(bF);
                eB += (int)__popcll(bB & ltm); tB += (int)__popcll(bB);
                eN += (int)__popcll(bN & ltm); tN += (int)__popcll(bN);
            }
            if (lane == 0) { w_f[wave] = tF; w_b[wave] = tB; w_n[wave] = tN; }
            int r0 = s_run[0], r1 = s_run[1], r2 = s_run[2];
            __syncthreads();   // A: wave totals visible

            int pf = 0, pb = 0, pn = 0;
            for (int w = 0; w < wave; ++w) { pf += w_f[w]; pb += w_b[w]; pn += w_n[w]; }
            int rF = r0 + pf + eF, rB = r1 + pb + eB, rN = r2 + pn + eN;
            #pragma unroll
            for (int j = 0; j < 16; ++j) {
                unsigned int c = (code >> (2 * j)) & 3u;
                int idx = idx0 + j;
                if (c == 1u) { if (rF < FG_CAP) l_fg[rF] = idx; rF++; }
                if (c == 2u) { if (rB < BG_CAP) l_bg[rB] = idx; rB++; }
                if (c <= 1u) { if (rN < NB_CAP) l_nb[rN] = idx; rN++; }
            }
            if (tid == 0) {
                s_run[0] += w_f[0] + w_f[1] + w_f[2] + w_f[3];
                s_run[1] += w_b[0] + w_b[1] + w_b[2] + w_b[3];
                s_run[2] += w_n[0] + w_n[1] + w_n[2] + w_n[3];
                if (s_run[0] >= FG_CAP && s_run[1] >= BG_CAP) s_stop = 1;
            }
            __syncthreads();   // B: run/stop + LDS lists visible
            if (s_stop) break;
        }

        // publish keep per slot (atomicExch = coherence-point store, no fence)
        int fgt = s_run[0], bgt = s_run[1];
        int fg_count = min(FG_CAP, fgt);
        int s = tid;                        // 256 threads == BATCH slots
        bool is_fg = (s < fg_count);
        int keep;
        if (is_fg) keep = l_fg[s];
        else { int j = s - fg_count; keep = (j < bgt) ? l_bg[j] : l_nb[j - bgt]; }
        atomicExch(&keep_arr[s], keep | (is_fg ? (1 << 30) : 0));
        return;
    }

    // ---------------- output blocks ----------------
    int s = (int)blockIdx.x - 1;
    __shared__ int sh_kv;
    if (tid == 0) {
        int kv = atomicAdd(&keep_arr[s], 0);        // coherent read
        while (kv == KV_SENTINEL) {
            __builtin_amdgcn_s_sleep(8);
            kv = atomicAdd(&keep_arr[s], 0);
        }
        sh_kv = kv;
    }
    __syncthreads();

    int kv = sh_kv;
    bool is_fg = (kv >> 30) & 1;
    int keep = kv & 0x3FFFFFFF;

    int assign = packed[keep] & 0xFFFF;             // same-addr loads broadcast
    int label = is_fg ? gtcls[assign] : 0;

    float4 roi = (keep < n_prop) ? ((const float4*)props)[keep]
                                 : ((const float4*)gtb)[keep - n_prop];
    float4 g = ((const float4*)gtb)[assign];

    float ew  = roi.z - roi.x + 1.0f;
    float eh  = roi.w - roi.y + 1.0f;
    float ecx = roi.x + 0.5f * ew;
    float ecy = roi.y + 0.5f * eh;
    float gw  = g.z - g.x + 1.0f;
    float gh  = g.w - g.y + 1.0f;
    float gcx = g.x + 0.5f * gw;
    float gcy = g.y + 0.5f * gh;
    float4 tv = make_float4((gcx - ecx) / ew, (gcy - ecy) / eh,
                            logf(gw / ew), logf(gh / eh));
    float4 zv = make_float4(0.f, 0.f, 0.f, 0.f);

    if (tid == 0) ((float4*)out)[s] = roi;          // rois (BATCH x 4)

    if (tid < C)                                     // labels one-hot (BATCH x C)
        out[4 * BATCH + (size_t)s * C + tid] = (tid == label) ? 1.0f : 0.0f;

    if (tid < C) {                                   // bbox_targets (C float4s/slot)
        float4* outb = (float4*)(out + 4 * BATCH + (size_t)BATCH * C) + (size_t)s * C;
        outb[tid] = (label > 0 && tid == label) ? tv : zv;
    }
}

extern "C" void kernel_launch(void* const* d_in, const int* in_sizes, int n_in,
                              void* d_out, int out_size, void* d_ws, size_t ws_size,
                              hipStream_t stream)
{
    const float* props = (const float*)d_in[0];   // (1, N, 4)
    const float* gtl   = (const float*)d_in[1];   // (1, K, C) one-hot
    const float* gtb   = (const float*)d_in[2];   // (1, K, 4)
    float* out = (float*)d_out;

    int n_prop  = in_sizes[0] / 4;
    int K       = in_sizes[2] / 4;
    int C       = in_sizes[1] / K;
    int n_total = n_prop + K;

    int* ws_packed = (int*)d_ws;                       // n_total ints (16B aligned)
    int* ws_gtcls  = ws_packed + ((n_total + 3) & ~3); // K ints
    int* ws_keep   = ws_gtcls + ((K + 3) & ~3);        // BATCH ints

    int roi_blocks = (n_total + ROIS_PB - 1) / ROIS_PB;
    int gt_blocks  = (K + 255) / 256;                  // covers K gtcls + BATCH sentinels (512 >= 256)

    pt_classify<<<roi_blocks + gt_blocks, 256, 0, stream>>>(
        props, gtb, gtl, ws_packed, ws_gtcls, ws_keep,
        n_prop, K, C, n_total, roi_blocks);
    pt_select_out<<<1 + BATCH, 256, 0, stream>>>(
        props, gtb, ws_packed, ws_gtcls, ws_keep,
        out, n_prop, K, C, n_total);
}

// Round 8
// 85.703 us; speedup vs baseline: 1.0208x; 1.0208x over previous
//
#include <hip/hip_runtime.h>

#define BATCH   256
#define FG_CAP  64
#define BG_CAP  192
#define NB_CAP  256
#define M_ROIS  2          // ROIs register-tiled per thread
#define GRP     8          // lanes per slice-group (k mod 8)
#define ROIS_PB (32 * M_ROIS)   // 64 ROIs per 256-thread block

// ---------------------------------------------------------------------------
// R8 = R6 verbatim (measured best: 85.7 µs, absmax 0.0).
// R5 (single-block output fusion, +11 µs) and R7 (poll-based producer/consumer
// fusion, +1.7 µs) both lost to this 3-dispatch structure: a ~2 µs dispatch
// gap is cheaper than any intra-kernel serial->parallel handoff here.
//
// Kernel 1: per-ROI IoU argmax vs all GT boxes. M=2 register tile: one
// ds_read_b128 feeds 2 roi-items (R5 analysis: 2 LDS instrs/item was the
// bottleneck), area_g recomputed per k with the identical _rn sequence
// (bit-identical, rides the VALU pipe). Division-free compare
// i_k*d_b > i_b*d_k (d>0); one __fdiv_rn on the winner reproduces numpy's
// rounded value at the 0.5/0.1 thresholds. packed[i] = bestk | cls<<16.
// ---------------------------------------------------------------------------
__global__ __launch_bounds__(256) void pt_classify(
    const float* __restrict__ props, const float* __restrict__ gtb,
    const float* __restrict__ gtl,
    int* __restrict__ packed, int* __restrict__ gtcls,
    int n_prop, int K, int C, int n_total, int roi_blocks)
{
    if ((int)blockIdx.x >= roi_blocks) {
        int t = ((int)blockIdx.x - roi_blocks) * 256 + (int)threadIdx.x;
        if (t < K) {
            const float* row = gtl + (size_t)t * C;
            float best = row[0]; int bc = 0;
            for (int c = 1; c < C; ++c) {
                float v = row[c];
                if (v > best) { best = v; bc = c; }
            }
            gtcls[t] = bc;
        }
        return;
    }

    __shared__ float4 s_gt[512];
    for (int k = threadIdx.x; k < K; k += 256)
        s_gt[k] = ((const float4*)gtb)[k];
    __syncthreads();

    const int grp   = (int)threadIdx.x >> 3;       // 0..31
    const int slice = (int)threadIdx.x & (GRP - 1);

    float4 a[M_ROIS]; float area_a[M_ROIS]; int ri[M_ROIS]; bool live[M_ROIS];
    #pragma unroll
    for (int m = 0; m < M_ROIS; ++m) {
        int i = (int)blockIdx.x * ROIS_PB + m * 32 + grp;
        ri[m] = i; live[m] = (i < n_total);
        if (live[m]) {
            a[m] = (i < n_prop) ? ((const float4*)props)[i]
                                : ((const float4*)gtb)[i - n_prop];
        } else {
            a[m] = make_float4(0.f, 0.f, 0.f, 0.f);
        }
        area_a[m] = __fmul_rn(__fadd_rn(__fsub_rn(a[m].z, a[m].x), 1.0f),
                              __fadd_rn(__fsub_rn(a[m].w, a[m].y), 1.0f));
    }

    float bi[M_ROIS], bd[M_ROIS]; int bk[M_ROIS];
    #pragma unroll
    for (int m = 0; m < M_ROIS; ++m) { bi[m] = -1.0f; bd[m] = 1.0f; bk[m] = 0x7FFFFFFF; }

    #pragma unroll 4
    for (int k = slice; k < K; k += GRP) {
        float4 g = s_gt[k];
        float area_g = __fmul_rn(__fadd_rn(__fsub_rn(g.z, g.x), 1.0f),
                                 __fadd_rn(__fsub_rn(g.w, g.y), 1.0f));
        #pragma unroll
        for (int m = 0; m < M_ROIS; ++m) {
            float iw = fmaxf(__fadd_rn(__fsub_rn(fminf(a[m].z, g.z), fmaxf(a[m].x, g.x)), 1.0f), 0.0f);
            float ih = fmaxf(__fadd_rn(__fsub_rn(fminf(a[m].w, g.w), fmaxf(a[m].y, g.y)), 1.0f), 0.0f);
            float inter = __fmul_rn(iw, ih);
            float denom = __fsub_rn(__fadd_rn(area_a[m], area_g), inter);
            if (inter * bd[m] > bi[m] * denom) { bi[m] = inter; bd[m] = denom; bk[m] = k; }
        }
    }

    // combine across the 8 slices of the group (ties -> lowest k)
    #pragma unroll
    for (int mask = 1; mask < GRP; mask <<= 1) {
        #pragma unroll
        for (int m = 0; m < M_ROIS; ++m) {
            float oi = __shfl_xor(bi[m], mask, 64);
            float od = __shfl_xor(bd[m], mask, 64);
            int   ok = __shfl_xor(bk[m], mask, 64);
            float lhs = oi * bd[m], rhs = bi[m] * od;
            if (lhs > rhs || (lhs == rhs && ok < bk[m])) { bi[m] = oi; bd[m] = od; bk[m] = ok; }
        }
    }

    if (slice == 0) {
        #pragma unroll
        for (int m = 0; m < M_ROIS; ++m) {
            if (live[m]) {
                float iou = __fdiv_rn(bi[m], bd[m]);
                int cls = 0;
                if (iou >= 0.5f)      cls = 1;
                else if (iou >= 0.1f) cls = 2;
                packed[ri[m]] = bk[m] | (cls << 16);
            }
        }
    }
}

// ---------------------------------------------------------------------------
// Kernel 2: stable index-ordered compaction (fg / bg / non-bg). R4-verified.
// 1024 threads, 8192 indices/round, ballot+popc ranks, early exit at
// 64 fg + 192 bg. Kernel boundary = free device-wide visibility of packed[].
// ---------------------------------------------------------------------------
__global__ __launch_bounds__(1024) void pt_compact(
    const int* __restrict__ packed,
    int* __restrict__ fg_list, int* __restrict__ bg_list,
    int* __restrict__ nb_list, int* __restrict__ counts, int n_total)
{
    __shared__ int w_f[16], w_b[16], w_n[16];
    __shared__ int s_run[3], s_stop;
    const int tid = (int)threadIdx.x;
    if (tid == 0) { s_run[0] = 0; s_run[1] = 0; s_run[2] = 0; s_stop = 0; }
    __syncthreads();

    const int lane = tid & 63, wave = tid >> 6;
    const unsigned long long ltm = (1ull << lane) - 1ull;

    for (int base = 0; base < n_total; base += 8192) {
        int idx0 = base + tid * 8;
        int code = 0;                       // 2 bits/item: 0 none, 1 fg, 2 bg, 3 oob
        if (idx0 + 7 < n_total) {
            int4 p0 = ((const int4*)packed)[idx0 >> 2];
            int4 p1 = ((const int4*)packed)[(idx0 >> 2) + 1];
            code  = (p0.x >> 16)        | ((p0.y >> 16) << 2)
                  | ((p0.z >> 16) << 4) | ((p0.w >> 16) << 6)
                  | ((p1.x >> 16) << 8) | ((p1.y >> 16) << 10)
                  | ((p1.z >> 16) << 12)| ((p1.w >> 16) << 14);
        } else {
            #pragma unroll
            for (int j = 0; j < 8; ++j) {
                int c = (idx0 + j < n_total) ? (packed[idx0 + j] >> 16) : 3;
                code |= c << (2 * j);
            }
        }

        int eF = 0, eB = 0, eN = 0, tF = 0, tB = 0, tN = 0;
        #pragma unroll
        for (int j = 0; j < 8; ++j) {
            int c = (code >> (2 * j)) & 3;
            unsigned long long bF = __ballot(c == 1);
            unsigned long long bB = __ballot(c == 2);
            unsigned long long bN = __ballot(c == 0 || c == 1);
            eF += (int)__popcll(bF & ltm); tF += (int)__popcll(bF);
            eB += (int)__popcll(bB & ltm); tB += (int)__popcll(bB);
            eN += (int)__popcll(bN & ltm); tN += (int)__popcll(bN);
        }
        if (lane == 0) { w_f[wave] = tF; w_b[wave] = tB; w_n[wave] = tN; }
        int r0 = s_run[0], r1 = s_run[1], r2 = s_run[2];
        __syncthreads();   // A: wave totals visible

        int pf = 0, pb = 0, pn = 0;
        for (int w = 0; w < wave; ++w) { pf += w_f[w]; pb += w_b[w]; pn += w_n[w]; }
        int rF = r0 + pf + eF, rB = r1 + pb + eB, rN = r2 + pn + eN;
        #pragma unroll
        for (int j = 0; j < 8; ++j) {
            int c = (code >> (2 * j)) & 3;
            int idx = idx0 + j;
            if (c == 1)           { if (rF < FG_CAP) fg_list[rF] = idx; rF++; }
            if (c == 2)           { if (rB < BG_CAP) bg_list[rB] = idx; rB++; }
            if (c == 0 || c == 1) { if (rN < NB_CAP) nb_list[rN] = idx; rN++; }
        }
        if (tid == 0) {
            int sf = 0, sb = 0, sn = 0;
            for (int w = 0; w < 16; ++w) { sf += w_f[w]; sb += w_b[w]; sn += w_n[w]; }
            s_run[0] += sf; s_run[1] += sb; s_run[2] += sn;
            if (s_run[0] >= FG_CAP && s_run[1] >= BG_CAP) s_stop = 1;
        }
        __syncthreads();   // B: run/stop update visible
        if (s_stop) break;
    }
    if (tid == 0) { counts[0] = s_run[0]; counts[1] = s_run[1]; counts[2] = s_run[2]; }
}

// ---------------------------------------------------------------------------
// Kernel 3: one block per output slot (device-wide parallel — R5 showed
// single-block output costs ~13 µs). rois (4), labels one-hot (C),
// bbox_targets (C float4s). Every element of d_out written (it's poisoned).
// ---------------------------------------------------------------------------
__global__ __launch_bounds__(128) void pt_output(
    const float* __restrict__ props, const float* __restrict__ gtb,
    const int* __restrict__ packed, const int* __restrict__ gtcls,
    const int* __restrict__ fg_list, const int* __restrict__ bg_list,
    const int* __restrict__ nb_list, const int* __restrict__ counts,
    float* __restrict__ out, int n_prop, int K, int C)
{
    __shared__ float sh[8];
    __shared__ int   sh_label;
    int s = blockIdx.x;

    if (threadIdx.x == 0) {
        int fg_total = counts[0], bg_total = counts[1];
        int fg_count = min(FG_CAP, fg_total);
        bool is_fg = (s < fg_count);
        int keep;
        if (is_fg) keep = fg_list[s];
        else { int j = s - fg_count; keep = (j < bg_total) ? bg_list[j] : nb_list[j - bg_total]; }
        int pk = packed[keep];
        int assign = pk & 0xFFFF;
        int label = is_fg ? gtcls[assign] : 0;

        float4 roi = (keep < n_prop) ? ((const float4*)props)[keep]
                                     : ((const float4*)gtb)[keep - n_prop];
        float4 g = ((const float4*)gtb)[assign];

        float ew  = roi.z - roi.x + 1.0f;
        float eh  = roi.w - roi.y + 1.0f;
        float ecx = roi.x + 0.5f * ew;
        float ecy = roi.y + 0.5f * eh;
        float gw  = g.z - g.x + 1.0f;
        float gh  = g.w - g.y + 1.0f;
        float gcx = g.x + 0.5f * gw;
        float gcy = g.y + 0.5f * gh;
        sh[0] = roi.x; sh[1] = roi.y; sh[2] = roi.z; sh[3] = roi.w;
        sh[4] = (gcx - ecx) / ew;
        sh[5] = (gcy - ecy) / eh;
        sh[6] = logf(gw / ew);
        sh[7] = logf(gh / eh);
        sh_label = label;
    }
    __syncthreads();

    int label = sh_label;

    if (threadIdx.x < 4) out[s * 4 + threadIdx.x] = sh[threadIdx.x];

    float* outl = out + 4 * BATCH;
    for (int c = threadIdx.x; c < C; c += 128)
        outl[s * C + c] = (c == label) ? 1.0f : 0.0f;

    float4* outb = (float4*)(out + 4 * BATCH + (size_t)BATCH * C) + (size_t)s * C;
    float4 tv = make_float4(sh[4], sh[5], sh[6], sh[7]);
    float4 zv = make_float4(0.f, 0.f, 0.f, 0.f);
    for (int c = threadIdx.x; c < C; c += 128)
        outb[c] = (label > 0 && c == label) ? tv : zv;
}

extern "C" void kernel_launch(void* const* d_in, const int* in_sizes, int n_in,
                              void* d_out, int out_size, void* d_ws, size_t ws_size,
                              hipStream_t stream)
{
    const float* props = (const float*)d_in[0];   // (1, N, 4)
    const float* gtl   = (const float*)d_in[1];   // (1, K, C) one-hot
    const float* gtb   = (const float*)d_in[2];   // (1, K, 4)
    float* out = (float*)d_out;

    int n_prop  = in_sizes[0] / 4;
    int K       = in_sizes[2] / 4;
    int C       = in_sizes[1] / K;
    int n_total = n_prop + K;

    int* ws_packed = (int*)d_ws;                       // n_total ints (16B aligned)
    int* ws_gtcls  = ws_packed + ((n_total + 3) & ~3); // K ints
    int* ws_fg     = ws_gtcls + ((K + 3) & ~3);        // FG_CAP
    int* ws_bg     = ws_fg + FG_CAP;                   // BG_CAP
    int* ws_nb     = ws_bg + BG_CAP;                   // NB_CAP
    int* ws_cnt    = ws_nb + NB_CAP;                   // 4

    int roi_blocks = (n_total + ROIS_PB - 1) / ROIS_PB;
    int gt_blocks  = (K + 255) / 256;

    pt_classify<<<roi_blocks + gt_blocks, 256, 0, stream>>>(
        props, gtb, gtl, ws_packed, ws_gtcls, n_prop, K, C, n_total, roi_blocks);
    pt_compact<<<1, 1024, 0, stream>>>(
        ws_packed, ws_fg, ws_bg, ws_nb, ws_cnt, n_total);
    pt_output<<<BATCH, 128, 0, stream>>>(
        props, gtb, ws_packed, ws_gtcls, ws_fg, ws_bg, ws_nb, ws_cnt,
        out, n_prop, K, C);
}